// Round 2
// baseline (311.970 us; speedup 1.0000x reference)
//
#include <hip/hip_runtime.h>

#define BB 8
#define TT 4096
#define FF 481
#define NF 96
#define FS 5

#define NHALF (NF / 2)                   // 48 f-pairs per (b,t) row
#define N_FILT2 (BB * TT * NHALF)        // 1,572,864 work items (2 outputs each)
#define N_HI    (BB * TT * (FF - NF))    // 12,615,680 complex pairs to copy
#define NBLK   4096
#define FB     1920                       // filter blocks; rest do the hi-copy

// nontemporal store of a float2 via double bit-cast (builtin rejects class types)
__device__ __forceinline__ void nt_store_f2(const float2 v, float2* p) {
    union { float2 f; double d; } u;
    u.f = v;
    __builtin_nontemporal_store(u.d, reinterpret_cast<double*>(p));
}

__global__ __launch_bounds__(256) void df_all(
    const float2* __restrict__ spec,   // (B,1,T,F) complex pairs
    const float2* __restrict__ coefs,  // (B,FS,T,NF) complex pairs
    float2* __restrict__ out)          // (B,1,T,F) complex pairs
{
    const unsigned bid = blockIdx.x;
    const unsigned tid = threadIdx.x;

    if (bid < FB) {
        // ---- deep-filter region: each thread does f and f+1 (f even) ----
        const unsigned stride = FB * 256u;
        for (unsigned n = bid * 256u + tid; n < (unsigned)N_FILT2; n += stride) {
            const unsigned fh = n % (unsigned)NHALF;
            const unsigned bt = n / (unsigned)NHALF;   // b*T + t
            const unsigned t  = bt & (TT - 1u);
            const unsigned f  = fh * 2u;
            const unsigned b  = bt >> 12;

            // coefs base: ((b*FS + i)*T + t)*NF + f ; i-step = TT*NF
            const float2* __restrict__ cp =
                coefs + (b * (unsigned)(FS * TT) + t) * (unsigned)NF + f;

            float ax = 0.f, ay = 0.f, bx = 0.f, by = 0.f;

            if (t >= FS - 1u) {
                // spec row for tap i is simply bt + i - (FS-1)
                const unsigned sbase = (bt - (FS - 1u)) * (unsigned)FF + f;
#pragma unroll
                for (int i = 0; i < FS; ++i) {
                    const float2 s0 = spec[sbase + (unsigned)(i * FF)];
                    const float2 s1 = spec[sbase + (unsigned)(i * FF) + 1u];
                    const float4 c4 = *reinterpret_cast<const float4*>(cp + i * (TT * NF));
                    ax = fmaf(s0.x, c4.x, ax); ax = fmaf(-s0.y, c4.y, ax);
                    ay = fmaf(s0.x, c4.y, ay); ay = fmaf(s0.y, c4.x, ay);
                    bx = fmaf(s1.x, c4.z, bx); bx = fmaf(-s1.y, c4.w, bx);
                    by = fmaf(s1.x, c4.w, by); by = fmaf(s1.y, c4.z, by);
                }
            } else {
                // cold boundary rows (t < 4): per-tap validity check
#pragma unroll
                for (int i = 0; i < FS; ++i) {
                    if ((int)t + i < FS - 1) continue;
                    const unsigned row = bt + (unsigned)i - (FS - 1u);
                    const float2 s0 = spec[row * (unsigned)FF + f];
                    const float2 s1 = spec[row * (unsigned)FF + f + 1u];
                    const float4 c4 = *reinterpret_cast<const float4*>(cp + i * (TT * NF));
                    ax = fmaf(s0.x, c4.x, ax); ax = fmaf(-s0.y, c4.y, ax);
                    ay = fmaf(s0.x, c4.y, ay); ay = fmaf(s0.y, c4.x, ay);
                    bx = fmaf(s1.x, c4.z, bx); bx = fmaf(-s1.y, c4.w, bx);
                    by = fmaf(s1.x, c4.w, by); by = fmaf(s1.y, c4.z, by);
                }
            }
            float2 r0; r0.x = ax; r0.y = ay;
            float2 r1; r1.x = bx; r1.y = by;
            const unsigned o = bt * (unsigned)FF + f;
            nt_store_f2(r0, &out[o]);
            nt_store_f2(r1, &out[o + 1u]);
        }
    } else {
        // ---- passthrough region: f in [96,481), unrolled x4 for MLP ----
        const unsigned stride = (NBLK - FB) * 256u;
        unsigned n = (bid - FB) * 256u + tid;

        while (n + 3u * stride < (unsigned)N_HI) {
            const unsigned n0 = n;
            const unsigned n1 = n + stride;
            const unsigned n2 = n + 2u * stride;
            const unsigned n3 = n + 3u * stride;
            const unsigned i0 = (n0 / 385u) * (unsigned)FF + (unsigned)NF + n0 % 385u;
            const unsigned i1 = (n1 / 385u) * (unsigned)FF + (unsigned)NF + n1 % 385u;
            const unsigned i2 = (n2 / 385u) * (unsigned)FF + (unsigned)NF + n2 % 385u;
            const unsigned i3 = (n3 / 385u) * (unsigned)FF + (unsigned)NF + n3 % 385u;
            const float2 v0 = spec[i0];
            const float2 v1 = spec[i1];
            const float2 v2 = spec[i2];
            const float2 v3 = spec[i3];
            nt_store_f2(v0, &out[i0]);
            nt_store_f2(v1, &out[i1]);
            nt_store_f2(v2, &out[i2]);
            nt_store_f2(v3, &out[i3]);
            n += 4u * stride;
        }
        for (; n < (unsigned)N_HI; n += stride) {
            const unsigned i = (n / 385u) * (unsigned)FF + (unsigned)NF + n % 385u;
            const float2 v = spec[i];
            nt_store_f2(v, &out[i]);
        }
    }
}

extern "C" void kernel_launch(void* const* d_in, const int* in_sizes, int n_in,
                              void* d_out, int out_size, void* d_ws, size_t ws_size,
                              hipStream_t stream) {
    const float2* spec  = (const float2*)d_in[0];
    const float2* coefs = (const float2*)d_in[1];
    float2* out = (float2*)d_out;

    df_all<<<dim3(NBLK), dim3(256), 0, stream>>>(spec, coefs, out);
}

// Round 5
// 306.082 us; speedup vs baseline: 1.0192x; 1.0192x over previous
//
#include <hip/hip_runtime.h>

#define BB 8
#define TT 4096
#define FF 481
#define NF 96
#define FS 5

#define N_FILT (BB * TT * NF)          // 3,145,728 complex pairs
#define N_HI   (BB * TT * (FF - NF))   // 12,615,680 complex pairs
#define NBLK   4096
#define FB     1920                     // filter blocks; rest do the hi-copy

__global__ __launch_bounds__(256) void df_all(
    const float2* __restrict__ spec,   // (B,1,T,F) complex pairs
    const float2* __restrict__ coefs,  // (B,FS,T,NF) complex pairs
    float2* __restrict__ out)          // (B,1,T,F) complex pairs
{
    const unsigned bid = blockIdx.x;
    const unsigned tid = threadIdx.x;

    if (bid < FB) {
        // ---- deep-filter region: f in [0,96) — R0 form, 1 output/thread ----
        const unsigned stride = FB * 256u;
        for (unsigned n = bid * 256u + tid; n < (unsigned)N_FILT; n += stride) {
            const unsigned f  = n % (unsigned)NF;
            const unsigned bt = n / (unsigned)NF;       // b*T + t
            const unsigned t  = bt & (TT - 1u);
            const unsigned b  = bt >> 12;

            float accx = 0.f, accy = 0.f;
#pragma unroll
            for (int i = 0; i < FS; ++i) {
                const int ts = (int)t + i - (FS - 1);
                if (ts < 0) continue;
                const float2 s = spec[(b * TT + (unsigned)ts) * FF + f];
                const float2 c = coefs[((b * FS + (unsigned)i) * TT + t) * NF + f];
                accx = fmaf(s.x, c.x, accx);
                accx = fmaf(-s.y, c.y, accx);
                accy = fmaf(s.x, c.y, accy);
                accy = fmaf(s.y, c.x, accy);
            }
            float2 r; r.x = accx; r.y = accy;
            out[bt * FF + f] = r;
        }
    } else {
        // ---- passthrough region: f in [96,481), unrolled x4 for MLP ----
        const unsigned stride = (NBLK - FB) * 256u;
        unsigned n = (bid - FB) * 256u + tid;

        while (n + 3u * stride < (unsigned)N_HI) {
            const unsigned n1 = n + stride;
            const unsigned n2 = n + 2u * stride;
            const unsigned n3 = n + 3u * stride;
            const unsigned i0 = (n  / 385u) * (unsigned)FF + (unsigned)NF + n  % 385u;
            const unsigned i1 = (n1 / 385u) * (unsigned)FF + (unsigned)NF + n1 % 385u;
            const unsigned i2 = (n2 / 385u) * (unsigned)FF + (unsigned)NF + n2 % 385u;
            const unsigned i3 = (n3 / 385u) * (unsigned)FF + (unsigned)NF + n3 % 385u;
            const float2 v0 = spec[i0];
            const float2 v1 = spec[i1];
            const float2 v2 = spec[i2];
            const float2 v3 = spec[i3];
            out[i0] = v0;
            out[i1] = v1;
            out[i2] = v2;
            out[i3] = v3;
            n += 4u * stride;
        }
        for (; n < (unsigned)N_HI; n += stride) {
            const unsigned i = (n / 385u) * (unsigned)FF + (unsigned)NF + n % 385u;
            out[i] = spec[i];
        }
    }
}

extern "C" void kernel_launch(void* const* d_in, const int* in_sizes, int n_in,
                              void* d_out, int out_size, void* d_ws, size_t ws_size,
                              hipStream_t stream) {
    const float2* spec  = (const float2*)d_in[0];
    const float2* coefs = (const float2*)d_in[1];
    float2* out = (float2*)d_out;

    df_all<<<dim3(NBLK), dim3(256), 0, stream>>>(spec, coefs, out);
}